// Round 4
// baseline (1188.514 us; speedup 1.0000x reference)
//
#include <hip/hip_runtime.h>

#define T_DIM 4096
#define D_DIM 2048
#define H_DIM 32
#define DH    64
#define CHUNK 64
#define NCHUNK (T_DIM / CHUNK)
#define EPS 1e-5f

typedef __attribute__((ext_vector_type(8))) short short8;
typedef __attribute__((ext_vector_type(4))) float f32x4;

// ----------------------------------------------------------- bf16 split utils
__device__ inline ushort f2bf(float f) {
  uint u = __float_as_uint(f);
  u += 0x7FFF + ((u >> 16) & 1);          // RNE
  return (ushort)(u >> 16);
}
__device__ inline float bf2f(ushort h) { return __uint_as_float(((uint)h) << 16); }
__device__ inline void split2(float f, ushort& hi, ushort& lo) {
  hi = f2bf(f);
  lo = f2bf(f - bf2f(hi));
}

// ---------------------------------------------------------------- LN helper
__device__ inline void block_reduce_2(float& s1, float& s2) {
  __shared__ float red[8];
  #pragma unroll
  for (int off = 32; off > 0; off >>= 1) {
    s1 += __shfl_down(s1, off, 64);
    s2 += __shfl_down(s2, off, 64);
  }
  int lane = threadIdx.x & 63, wid = threadIdx.x >> 6;
  if (lane == 0) { red[wid] = s1; red[4 + wid] = s2; }
  __syncthreads();
  s1 = red[0] + red[1] + red[2] + red[3];
  s2 = red[4] + red[5] + red[6] + red[7];
}

// LN over rows of length D_DIM; emits SPLIT bf16 (hi, lo) for GEMM A-input.
// If Add != nullptr: input = X + Add, pre-LN sum stored fp32 to Yout
// (Yout may alias Add: same-thread read-before-write at same offsets).
__global__ __launch_bounds__(256) void ln_fwd(
    const float* __restrict__ X, const float* Add, float* Yout,
    const float* __restrict__ w, const float* __restrict__ b,
    ushort* __restrict__ out_hi, ushort* __restrict__ out_lo) {
  const int row = blockIdx.x;
  const size_t base = (size_t)row * D_DIM;
  const int t = threadIdx.x;

  float4 v0 = *(const float4*)(X + base + (size_t)t * 4);
  float4 v1 = *(const float4*)(X + base + (size_t)(t + 256) * 4);
  if (Add) {
    float4 a0 = *(const float4*)(Add + base + (size_t)t * 4);
    float4 a1 = *(const float4*)(Add + base + (size_t)(t + 256) * 4);
    v0.x += a0.x; v0.y += a0.y; v0.z += a0.z; v0.w += a0.w;
    v1.x += a1.x; v1.y += a1.y; v1.z += a1.z; v1.w += a1.w;
    *(float4*)(Yout + base + (size_t)t * 4) = v0;
    *(float4*)(Yout + base + (size_t)(t + 256) * 4) = v1;
  }
  float s  = v0.x + v0.y + v0.z + v0.w + v1.x + v1.y + v1.z + v1.w;
  float ss = v0.x*v0.x + v0.y*v0.y + v0.z*v0.z + v0.w*v0.w
           + v1.x*v1.x + v1.y*v1.y + v1.z*v1.z + v1.w*v1.w;
  block_reduce_2(s, ss);
  const float m   = s * (1.0f / D_DIM);
  const float var = ss * (1.0f / D_DIM) - m * m;
  const float r   = rsqrtf(var + EPS);

  float4 w0 = *(const float4*)(w + (size_t)t * 4);
  float4 w1 = *(const float4*)(w + (size_t)(t + 256) * 4);
  float4 b0 = *(const float4*)(b + (size_t)t * 4);
  float4 b1 = *(const float4*)(b + (size_t)(t + 256) * 4);
  float o[8];
  o[0] = (v0.x - m) * r * w0.x + b0.x;
  o[1] = (v0.y - m) * r * w0.y + b0.y;
  o[2] = (v0.z - m) * r * w0.z + b0.z;
  o[3] = (v0.w - m) * r * w0.w + b0.w;
  o[4] = (v1.x - m) * r * w1.x + b1.x;
  o[5] = (v1.y - m) * r * w1.y + b1.y;
  o[6] = (v1.z - m) * r * w1.z + b1.z;
  o[7] = (v1.w - m) * r * w1.w + b1.w;
  ushort h[8], l[8];
  #pragma unroll
  for (int j = 0; j < 8; ++j) split2(o[j], h[j], l[j]);
  *(ushort4*)(out_hi + base + (size_t)t * 4) = make_ushort4(h[0], h[1], h[2], h[3]);
  *(ushort4*)(out_lo + base + (size_t)t * 4) = make_ushort4(l[0], l[1], l[2], l[3]);
  *(ushort4*)(out_hi + base + (size_t)(t + 256) * 4) = make_ushort4(h[4], h[5], h[6], h[7]);
  *(ushort4*)(out_lo + base + (size_t)(t + 256) * 4) = make_ushort4(l[4], l[5], l[6], l[7]);
}

// ----------------------------------- weight transpose + bf16 split (JIT, 64x64)
// W [KR][NC] fp32 -> WT_hi/WT_lo [NC][KR] bf16
__global__ __launch_bounds__(256) void tsplit(
    const float* __restrict__ W, ushort* __restrict__ WTh,
    ushort* __restrict__ WTl, int KR, int NC) {
  __shared__ float tile[64][65];
  const int t = threadIdx.x;
  const int k0 = blockIdx.y * 64, n0 = blockIdx.x * 64;
  #pragma unroll
  for (int p = 0; p < 4; ++p) {
    int r = (t >> 4) + p * 16;
    int c = (t & 15) * 4;
    *(float4*)&tile[r][c] = *(const float4*)&W[(size_t)(k0 + r) * NC + n0 + c];
  }
  __syncthreads();
  #pragma unroll
  for (int p = 0; p < 4; ++p) {
    int n = (t >> 4) + p * 16;       // local out row (n)
    int c = (t & 15) * 4;            // local out col base (k)
    ushort h[4], l[4];
    #pragma unroll
    for (int j = 0; j < 4; ++j) split2(tile[c + j][n], h[j], l[j]);
    size_t off = (size_t)(n0 + n) * KR + k0 + c;
    *(ushort4*)(WTh + off) = make_ushort4(h[0], h[1], h[2], h[3]);
    *(ushort4*)(WTl + off) = make_ushort4(l[0], l[1], l[2], l[3]);
  }
}

// ------------------------------------------- split-bf16 MFMA GEMM (3 products)
// C[M,N] = A[M,K] @ B[K,N] (+Add), A given as hi/lo bf16 [M][K],
// B given as TRANSPOSED hi/lo bf16 [N][K]. C fp32 (may alias Add).
#define LDT 40   // LDS row stride in ushorts (80B): slot = 5r mod 8 -> 2-way free
__global__ __launch_bounds__(256) void gemm_bf16s(
    const ushort* __restrict__ Ah, const ushort* __restrict__ Al,
    const ushort* __restrict__ Bh, const ushort* __restrict__ Bl,
    const float* Add, float* __restrict__ C, int M, int N, int K) {
  __shared__ ushort Ash[128 * LDT];
  __shared__ ushort Asl[128 * LDT];
  __shared__ ushort Bsh[128 * LDT];
  __shared__ ushort Bsl[128 * LDT];
  const int tid = threadIdx.x;

  // Bijective XCD-aware swizzle of flattened block id (grids are %8==0).
  int bxs = blockIdx.x, bys = blockIdx.y;
  {
    int gx = gridDim.x, n = gx * gridDim.y;
    int lid = bys * gx + bxs;
    if ((n & 7) == 0) {
      int cpx = n >> 3;
      lid = (lid & 7) * cpx + (lid >> 3);
      bys = lid / gx;
      bxs = lid - bys * gx;
    }
  }
  const int bm = bys * 128, bn = bxs * 128;

  // staging assignment: thread t -> tile row r = t>>1, k-half h = t&1 (16 elems)
  const int r = tid >> 1, h = tid & 1;
  float4 pa0, pa1, pl0, pl1, pb0, pb1, pm0, pm1;

#define LOAD_TILES(K0) do {                                            \
    size_t aoff = (size_t)(bm + r) * K + (size_t)(K0) + h * 16;        \
    pa0 = *(const float4*)(Ah + aoff); pa1 = *(const float4*)(Ah + aoff + 8); \
    pl0 = *(const float4*)(Al + aoff); pl1 = *(const float4*)(Al + aoff + 8); \
    size_t boff = (size_t)(bn + r) * K + (size_t)(K0) + h * 16;        \
    pb0 = *(const float4*)(Bh + boff); pb1 = *(const float4*)(Bh + boff + 8); \
    pm0 = *(const float4*)(Bl + boff); pm1 = *(const float4*)(Bl + boff + 8); \
  } while (0)

#define STORE_TILES() do {                                             \
    ushort* wa = Ash + r * LDT + h * 16;                               \
    *(float4*)wa = pa0; *(float4*)(wa + 8) = pa1;                      \
    ushort* wl = Asl + r * LDT + h * 16;                               \
    *(float4*)wl = pl0; *(float4*)(wl + 8) = pl1;                      \
    ushort* wb = Bsh + r * LDT + h * 16;                               \
    *(float4*)wb = pb0; *(float4*)(wb + 8) = pb1;                      \
    ushort* wm = Bsl + r * LDT + h * 16;                               \
    *(float4*)wm = pm0; *(float4*)(wm + 8) = pm1;                      \
  } while (0)

  const int lane = tid & 63, wv = tid >> 6;
  const int wm_ = (wv >> 1) * 64, wn_ = (wv & 1) * 64;
  const int ln = lane & 15, kg = lane >> 4;

  f32x4 acc[4][4];
  #pragma unroll
  for (int i = 0; i < 4; ++i)
    #pragma unroll
    for (int j = 0; j < 4; ++j) {
      f32x4 z = {0.f, 0.f, 0.f, 0.f};
      acc[i][j] = z;
    }

  LOAD_TILES(0);
  STORE_TILES();
  __syncthreads();

  for (int k0 = 0; k0 < K; k0 += 32) {
    const bool more = (k0 + 32) < K;
    if (more) LOAD_TILES(k0 + 32);

    short8 fah[4], fal[4], fbh[4], fbl[4];
    #pragma unroll
    for (int i = 0; i < 4; ++i) {
      fah[i] = *(const short8*)(Ash + (wm_ + i * 16 + ln) * LDT + kg * 8);
      fal[i] = *(const short8*)(Asl + (wm_ + i * 16 + ln) * LDT + kg * 8);
      fbh[i] = *(const short8*)(Bsh + (wn_ + i * 16 + ln) * LDT + kg * 8);
      fbl[i] = *(const short8*)(Bsl + (wn_ + i * 16 + ln) * LDT + kg * 8);
    }
    #pragma unroll
    for (int i = 0; i < 4; ++i)
      #pragma unroll
      for (int j = 0; j < 4; ++j) {
        acc[i][j] = __builtin_amdgcn_mfma_f32_16x16x32_bf16(fah[i], fbh[j], acc[i][j], 0, 0, 0);
        acc[i][j] = __builtin_amdgcn_mfma_f32_16x16x32_bf16(fah[i], fbl[j], acc[i][j], 0, 0, 0);
        acc[i][j] = __builtin_amdgcn_mfma_f32_16x16x32_bf16(fal[i], fbh[j], acc[i][j], 0, 0, 0);
      }
    __syncthreads();
    if (more) {
      STORE_TILES();
      __syncthreads();
    }
  }

  // epilogue: C/D layout col=lane&15, row=(lane>>4)*4+reg (m89-verified)
  #pragma unroll
  for (int i = 0; i < 4; ++i)
    #pragma unroll
    for (int j = 0; j < 4; ++j) {
      #pragma unroll
      for (int rg = 0; rg < 4; ++rg) {
        int row = bm + wm_ + i * 16 + kg * 4 + rg;
        int col = bn + wn_ + j * 16 + ln;
        size_t off = (size_t)row * N + col;
        float v = acc[i][j][rg];
        if (Add) v += Add[off];
        C[off] = v;
      }
    }
#undef LOAD_TILES
#undef STORE_TILES
}

// ------------------------------------------------- per-chunk  sum k_s (x) v_s
__global__ __launch_bounds__(256) void chunk_kv_sums(
    const float* __restrict__ Km, const float* __restrict__ Vm,
    float* __restrict__ S) {
  __shared__ float Ks[CHUNK][DH];
  __shared__ float Vs[CHUNK][DH];
  const int c = blockIdx.x, hh = blockIdx.y, tid = threadIdx.x;
  #pragma unroll
  for (int l = 0; l < 4; ++l) {
    int idx = tid + l * 256;
    int s = idx >> 4, c4 = (idx & 15) << 2;
    size_t g = (size_t)(c * CHUNK + s) * D_DIM + hh * DH + c4;
    *(float4*)&Ks[s][c4] = *(const float4*)(Km + g);
    *(float4*)&Vs[s][c4] = *(const float4*)(Vm + g);
  }
  __syncthreads();
  const int i0 = (tid >> 4) << 2;
  const int j0 = (tid & 15) << 2;
  float acc[4][4] = {};
  for (int s = 0; s < CHUNK; ++s) {
    float kv[4], vv[4];
    *(float4*)kv = *(const float4*)&Ks[s][i0];
    *(float4*)vv = *(const float4*)&Vs[s][j0];
    #pragma unroll
    for (int ii = 0; ii < 4; ++ii)
      #pragma unroll
      for (int jj = 0; jj < 4; ++jj)
        acc[ii][jj] = fmaf(kv[ii], vv[jj], acc[ii][jj]);
  }
  const size_t base = ((size_t)c * H_DIM + hh) * (DH * DH);
  #pragma unroll
  for (int ii = 0; ii < 4; ++ii)
    *(float4*)&S[base + (size_t)(i0 + ii) * DH + j0] =
        make_float4(acc[ii][0], acc[ii][1], acc[ii][2], acc[ii][3]);
}

// --------------------------- exclusive prefix over chunks (in place) + final
__global__ __launch_bounds__(256) void state_scan(
    const float* __restrict__ st0, const float* __restrict__ gamma,
    float* __restrict__ S, float* __restrict__ fs_out) {
  const int hh = blockIdx.y;
  const int e = blockIdx.x * 256 + threadIdx.x;
  float run = st0[(size_t)hh * 4096 + e];
  for (int c = 0; c < NCHUNK; ++c) {
    size_t idx = ((size_t)c * H_DIM + hh) * 4096 + e;
    float tmp = S[idx];
    S[idx] = run;
    run += tmp;
  }
  const int i = e >> 6;
  fs_out[(size_t)hh * 4096 + e] = run + (float)T_DIM * gamma[hh * DH + i];
}

// ------------------------------------------------------- per-chunk attention
__global__ __launch_bounds__(256) void attn_intra(
    const float* __restrict__ Qm, const float* __restrict__ Km,
    const float* __restrict__ Vm, const float* __restrict__ M,
    const float* __restrict__ gamma, float* __restrict__ O) {
  __shared__ float Qs[CHUNK * DH];
  __shared__ float Bf[CHUNK * DH];
  __shared__ float As[CHUNK * CHUNK];
  __shared__ float Sq[CHUNK];
  const int c = blockIdx.x, hh = blockIdx.y, tid = threadIdx.x;

  #pragma unroll
  for (int l = 0; l < 4; ++l) {
    int idx = tid + l * 256;
    int r = idx >> 4, c4 = (idx & 15) << 2;
    size_t g = (size_t)(c * CHUNK + r) * D_DIM + hh * DH + c4;
    *(float4*)&Qs[r * DH + c4] = *(const float4*)(Qm + g);
    float4 vv = *(const float4*)(Vm + g);
    Bf[(c4 + 0) * CHUNK + r] = vv.x;
    Bf[(c4 + 1) * CHUNK + r] = vv.y;
    Bf[(c4 + 2) * CHUNK + r] = vv.z;
    Bf[(c4 + 3) * CHUNK + r] = vv.w;
  }
  __syncthreads();
  if (tid < CHUNK) {
    float s = 0.f;
    for (int j = 0; j < DH; ++j) s += Qs[tid * DH + j];
    Sq[tid] = s;
  }
  #pragma unroll
  for (int rr = 0; rr < 16; ++rr) {
    int p = tid + rr * 256;
    int t = p >> 6, s = p & 63;
    float a = 0.f;
    for (int j = 0; j < DH; ++j)
      a = fmaf(Qs[t * DH + j], Bf[j * CHUNK + s], a);
    As[t * CHUNK + s] = a;
  }
  __syncthreads();
  #pragma unroll
  for (int l = 0; l < 4; ++l) {
    int idx = tid + l * 256;
    int r = idx >> 4, c4 = (idx & 15) << 2;
    size_t g = (size_t)(c * CHUNK + r) * D_DIM + hh * DH + c4;
    *(float4*)&Bf[r * DH + c4] = *(const float4*)(Km + g);
  }
  __syncthreads();
  const int i = tid & 63, tg = tid >> 6;
  float acc[16];
  #pragma unroll
  for (int rr = 0; rr < 16; ++rr) {
    int t = rr * 4 + tg;
    float o = 0.f;
    for (int s = 0; s <= t; ++s)
      o = fmaf(As[t * CHUNK + s], Bf[s * DH + i], o);
    acc[rr] = o;
  }
  __syncthreads();
  #pragma unroll
  for (int l = 0; l < 4; ++l) {
    int idx = tid + l * 256;
    int r = idx >> 4, c4 = (idx & 15) << 2;
    size_t g = ((size_t)c * H_DIM + hh) * 4096 + (size_t)r * DH + c4;
    float4 mv = *(const float4*)(M + g);
    Bf[(c4 + 0) * DH + r] = mv.x;
    Bf[(c4 + 1) * DH + r] = mv.y;
    Bf[(c4 + 2) * DH + r] = mv.z;
    Bf[(c4 + 3) * DH + r] = mv.w;
  }
  __syncthreads();
  const float gi = gamma[hh * DH + i];
  #pragma unroll
  for (int rr = 0; rr < 16; ++rr) {
    int t = rr * 4 + tg;
    float o = acc[rr];
    for (int j = 0; j < DH; ++j)
      o = fmaf(Qs[t * DH + j], Bf[j * DH + i], o);
    o = fmaf((float)(c * CHUNK + t + 1) * gi, Sq[t], o);
    O[(size_t)(c * CHUNK + t) * D_DIM + hh * DH + i] = o;
  }
}

// ------------------------------------------------------------- gated SiLU
__device__ inline float sigf(float x) { return 1.0f / (1.0f + expf(-x)); }

__global__ __launch_bounds__(256) void gate_act(
    const float* __restrict__ G, ushort* __restrict__ Mh,
    ushort* __restrict__ Ml) {
  const int n4 = T_DIM * (D_DIM / 4);
  for (int p = blockIdx.x * 256 + threadIdx.x; p < n4; p += gridDim.x * 256) {
    int t = p / (D_DIM / 4);
    int d = (p % (D_DIM / 4)) * 4;
    size_t gbase = (size_t)t * (2 * D_DIM) + d;
    float4 gv = *(const float4*)(G + gbase);
    float4 mv = *(const float4*)(G + gbase + D_DIM);
    float rr[4];
    rr[0] = mv.x * sigf(mv.x) * sigf(gv.x);
    rr[1] = mv.y * sigf(mv.y) * sigf(gv.y);
    rr[2] = mv.z * sigf(mv.z) * sigf(gv.z);
    rr[3] = mv.w * sigf(mv.w) * sigf(gv.w);
    ushort h[4], l[4];
    #pragma unroll
    for (int j = 0; j < 4; ++j) split2(rr[j], h[j], l[j]);
    size_t off = (size_t)t * D_DIM + d;
    *(ushort4*)(Mh + off) = make_ushort4(h[0], h[1], h[2], h[3]);
    *(ushort4*)(Ml + off) = make_ushort4(l[0], l[1], l[2], l[3]);
  }
}

// ---------------------------------------------------------------- launcher
// ws layout (5 * TD floats = 160 MB):
//   [0,TD):    ACT  split-bf16 act (XN -> X2) ; also S (fp32, TD floats) between
//   [TD,2TD):  Q fp32            -> G low half
//   [2TD,3TD): Kb fp32           -> G high half
//   [3TD,4TD): Vb fp32           -> Min split-bf16
//   [4TD,5TD): WT split-bf16 (JIT per-weight transpose, reused 5x)
// O and Y live in d_out (every element written before read each launch).
extern "C" void kernel_launch(void* const* d_in, const int* in_sizes, int n_in,
                              void* d_out, int out_size, void* d_ws, size_t ws_size,
                              hipStream_t stream) {
  const float* x     = (const float*)d_in[0];
  const float* st0   = (const float*)d_in[1];
  const float* Wq    = (const float*)d_in[2];
  const float* Wk    = (const float*)d_in[3];
  const float* Wv    = (const float*)d_in[4];
  const float* gamma = (const float*)d_in[5];
  const float* Wgate = (const float*)d_in[6];
  const float* Wdown = (const float*)d_in[7];
  const float* ln1w  = (const float*)d_in[8];
  const float* ln1b  = (const float*)d_in[9];
  const float* ln2w  = (const float*)d_in[10];
  const float* ln2b  = (const float*)d_in[11];

  const size_t TD = (size_t)T_DIM * D_DIM;   // 8M elems
  if (ws_size < 5 * TD * sizeof(float)) return;  // clean, visible failure

  float* out    = (float*)d_out;
  float* fs_out = out + TD;

  float* ws = (float*)d_ws;
  ushort* ACTh = (ushort*)ws;            // TD ushorts
  ushort* ACTl = ACTh + TD;
  float*  Q    = ws + TD;
  float*  Kb   = ws + 2 * TD;
  float*  Vb   = ws + 3 * TD;
  ushort* WTh  = (ushort*)(ws + 4 * TD);
  ushort* WTl  = WTh + TD;
  float*  S    = ws;                     // reuses ACT (dead after QKV gemms)
  float*  G    = Q;                      // spans Q..Kb (2TD floats)
  ushort* Mh   = (ushort*)Vb;
  ushort* Ml   = Mh + TD;
  float*  O    = out;
  float*  Y    = out;

  dim3 blk(256);
  dim3 gQKV(16, 32), gGate(32, 32);
  dim3 tsq(32, 32), tsg(64, 32);

  // LN1 -> split activations
  ln_fwd<<<T_DIM, blk, 0, stream>>>(x, nullptr, nullptr, ln1w, ln1b, ACTh, ACTl);

  // QKV GEMMs (JIT weight transpose+split each)
  tsplit<<<tsq, blk, 0, stream>>>(Wq, WTh, WTl, D_DIM, D_DIM);
  gemm_bf16s<<<gQKV, blk, 0, stream>>>(ACTh, ACTl, WTh, WTl, nullptr, Q,  T_DIM, D_DIM, D_DIM);
  tsplit<<<tsq, blk, 0, stream>>>(Wk, WTh, WTl, D_DIM, D_DIM);
  gemm_bf16s<<<gQKV, blk, 0, stream>>>(ACTh, ACTl, WTh, WTl, nullptr, Kb, T_DIM, D_DIM, D_DIM);
  tsplit<<<tsq, blk, 0, stream>>>(Wv, WTh, WTl, D_DIM, D_DIM);
  gemm_bf16s<<<gQKV, blk, 0, stream>>>(ACTh, ACTl, WTh, WTl, nullptr, Vb, T_DIM, D_DIM, D_DIM);

  // linear-attention path (fp32)
  chunk_kv_sums<<<dim3(NCHUNK, H_DIM), blk, 0, stream>>>(Kb, Vb, S);
  state_scan<<<dim3(16, H_DIM), blk, 0, stream>>>(st0, gamma, S, fs_out);
  attn_intra<<<dim3(NCHUNK, H_DIM), blk, 0, stream>>>(Q, Kb, Vb, S, gamma, O);

  // Y = x + O (in d_out), X2 = split-bf16 LN2(Y)
  ln_fwd<<<T_DIM, blk, 0, stream>>>(x, O, Y, ln2w, ln2b, ACTh, ACTl);

  // MLP
  tsplit<<<tsg, blk, 0, stream>>>(Wgate, WTh, WTl, D_DIM, 2 * D_DIM);
  gemm_bf16s<<<gGate, blk, 0, stream>>>(ACTh, ACTl, WTh, WTl, nullptr, G, T_DIM, 2 * D_DIM, D_DIM);
  gate_act<<<2048, blk, 0, stream>>>(G, Mh, Ml);
  tsplit<<<tsq, blk, 0, stream>>>(Wdown, WTh, WTl, D_DIM, D_DIM);
  // out = Min @ Wdown + Y (C aliases Add; same-offset read-before-write)
  gemm_bf16s<<<gQKV, blk, 0, stream>>>(Mh, Ml, WTh, WTl, Y, out, T_DIM, D_DIM, D_DIM);
}